// Round 9
// baseline (261.178 us; speedup 1.0000x reference)
//
#include <hip/hip_runtime.h>
#include <math.h>

#define BB 8
#define QQ 100
#define CC 41
#define TT 50
#define PP 12544        // = 49 * 256
#define QP 112          // padded Q rows (7 * 16)
#define TP 64           // padded T rows (4 * 16)
#define KS 8            // split-K over P
#define KCH (PP / KS)   // 1568
#define NT (BB * TT)    // 400
#define NMASK (NT + BB * QQ)   // 1200

typedef _Float16 f16x8 __attribute__((ext_vector_type(8)));
typedef float f32x4 __attribute__((ext_vector_type(4)));

// ---------------------------------------------------------------------------
// sort_kernel: block (b,bin) of 256 threads. Counting-sort batch b's points
// into 16 row-bins (bin = clamp(floor(y),0,255)>>4). Deterministic ballot-
// scan compaction; emits per-point gather table entries in sorted order:
//   t.x = r0*256+xb, t.y = r1*256+xb (element indices)
//   t.z = (wa,wb) f16x2  x-weights for m[xb], m[xb+1] (border-folded)
//   t.w = (ya,yb) f16x2  y-weights for rows r0, r1   (border-folded)
// ---------------------------------------------------------------------------
__global__ __launch_bounds__(256) void sort_kernel(
    const float* __restrict__ coords, uint4* __restrict__ stb)
{
    int b = blockIdx.x >> 4;
    int mybin = blockIdx.x & 15;
    int tid = threadIdx.x;
    int lane = tid & 63, w = tid >> 6;
    const float2* cd = (const float2*)coords + (size_t)b * PP;
    __shared__ int hist[16];
    __shared__ int woff[4];
    __shared__ int running;
    if (tid < 16) hist[tid] = 0;
    __syncthreads();
    for (int p = tid; p < PP; p += 256) {
        float y = fmaf(cd[p].y, 256.f, -0.5f);
        int y0 = (int)floorf(y);
        int bin = min(max(y0, 0), 255) >> 4;
        atomicAdd(&hist[bin], 1);
    }
    __syncthreads();
    int start = 0;
    for (int i = 0; i < mybin; ++i) start += hist[i];
    if (tid == 0) running = 0;
    __syncthreads();

    uint4* out = stb + (size_t)b * PP;
    for (int c = 0; c < 49; ++c) {
        int p = c * 256 + tid;
        float2 cc = cd[p];
        float x = fmaf(cc.x, 256.f, -0.5f);
        float y = fmaf(cc.y, 256.f, -0.5f);
        float x0f = floorf(x), y0f = floorf(y);
        int x0 = (int)x0f, y0 = (int)y0f;
        int bin = min(max(y0, 0), 255) >> 4;
        bool match = (bin == mybin);
        unsigned long long bal = __ballot(match);
        if (lane == 0) woff[w] = (int)__popcll(bal);
        __syncthreads();
        int wbase = 0;
        #pragma unroll
        for (int i = 0; i < 4; ++i) if (i < w) wbase += woff[i];
        int tot = woff[0] + woff[1] + woff[2] + woff[3];
        if (match) {
            int rk = (int)__popcll(bal & ((1ull << lane) - 1ull));
            float wx = x - x0f, wy = y - y0f;
            int xb = min(max(x0, 0), 254);
            int r0 = min(max(y0, 0), 255);
            int r1 = min(y0 + 1, 255);
            float wa, wb;
            if (x0 < 0)        { wa = wx;       wb = 0.f; }
            else if (x0 > 254) { wa = 0.f;      wb = 1.f - wx; }
            else               { wa = 1.f - wx; wb = wx; }
            float ya = (y0 >= 0)  ? 1.f - wy : 0.f;
            float yb = (y0 < 255) ? wy       : 0.f;
            union { unsigned int u; _Float16 h[2]; } pw, pyw;
            pw.h[0] = (_Float16)wa;  pw.h[1] = (_Float16)wb;
            pyw.h[0] = (_Float16)ya; pyw.h[1] = (_Float16)yb;
            uint4 t;
            t.x = (unsigned int)(r0 * 256 + xb);
            t.y = (unsigned int)(r1 * 256 + xb);
            t.z = pw.u; t.w = pyw.u;
            out[start + running + wbase + rk] = t;
        }
        __syncthreads();
        if (tid == 0) running += tot;
        __syncthreads();
    }
}

// ---------------------------------------------------------------------------
// sample_kernel: one block (512 thr) per mask. NO LDS staging — direct global
// gathers from the fp32 mask; sorted point order keeps the active window
// (~16 rows = 16 KB) L1/L2-resident. No barriers until the final reduction.
// ---------------------------------------------------------------------------
__global__ __launch_bounds__(512, 8) void sample_kernel(
    const float* __restrict__ tgt_masks, const float* __restrict__ pred_masks,
    const uint4* __restrict__ stb,
    _Float16* __restrict__ tm, _Float16* __restrict__ om, _Float16* __restrict__ sg,
    float* __restrict__ tmsum, float* __restrict__ nsum, float* __restrict__ ssum)
{
    __shared__ float red[8], red2[8];
    int id = blockIdx.x;
    int tid = threadIdx.x;
    bool is_t = id < NT;
    int b;
    const float* m;
    _Float16* dst;
    _Float16* dsg = nullptr;
    if (is_t) {
        b = id / TT;
        m = tgt_masks + (size_t)id * 65536;
        dst = tm + ((size_t)b * TP + (id % TT)) * PP;
    } else {
        int bq = id - NT;
        b = bq / QQ;
        m = pred_masks + (size_t)bq * 65536;
        dst = om + ((size_t)b * QP + (bq % QQ)) * PP;
        dsg = sg + ((size_t)b * QP + (bq % QQ)) * PP;
    }
    const uint4* tb = stb + (size_t)b * PP;

    float l1 = 0.f, l2 = 0.f;
    for (int p = tid; p < PP; p += 512) {
        uint4 t = tb[p];
        float v00 = m[t.x], v01 = m[t.x + 1];
        float v10 = m[t.y], v11 = m[t.y + 1];
        union { unsigned int u; _Float16 h[2]; } pw, pyw;
        pw.u = t.z; pyw.u = t.w;
        float wa = (float)pw.h[0], wb = (float)pw.h[1];
        float ya = (float)pyw.h[0], yb = (float)pyw.h[1];
        float v = ya * fmaf(wa, v00, wb * v01) + yb * fmaf(wa, v10, wb * v11);
        dst[p] = (_Float16)v;
        if (is_t) {
            l1 += v;
        } else {
            float e = __expf(-fabsf(v));
            float q = 1.f / (1.f + e);
            float g = (v >= 0.f) ? q : e * q;
            dsg[p] = (_Float16)g;
            l1 += fmaxf(v, 0.f) + __logf(1.f + e);
            l2 += g;
        }
    }

    #pragma unroll
    for (int off = 32; off; off >>= 1) {
        l1 += __shfl_down(l1, off, 64);
        l2 += __shfl_down(l2, off, 64);
    }
    if ((tid & 63) == 0) { red[tid >> 6] = l1; red2[tid >> 6] = l2; }
    __syncthreads();
    if (tid == 0) {
        float t1 = 0.f, t2 = 0.f;
        #pragma unroll
        for (int w = 0; w < 8; ++w) { t1 += red[w]; t2 += red2[w]; }
        if (is_t) tmsum[id] = t1;
        else { nsum[id - NT] = t1; ssum[id - NT] = t2; }
    }
}

// grid (7 qt, 8 b, KS). 4 waves; wave w owns t-tile w. C1=om.tm^T, C2=sig.tm^T.
__global__ __launch_bounds__(256) void dot_mfma_kernel(
    const _Float16* __restrict__ om, const _Float16* __restrict__ sg,
    const _Float16* __restrict__ tm,
    float* __restrict__ part_om, float* __restrict__ part_s)
{
    int qt = blockIdx.x, b = blockIdx.y, ks = blockIdx.z;
    int tid = threadIdx.x, lane = tid & 63, w = tid >> 6;
    int ra = lane & 15;
    int ko = (lane >> 4) * 8;
    const _Float16* pa = om + ((size_t)(b * QP + qt * 16 + ra)) * PP + ks * KCH + ko;
    const _Float16* ps = sg + ((size_t)(b * QP + qt * 16 + ra)) * PP + ks * KCH + ko;
    const _Float16* pb = tm + ((size_t)(b * TP + w * 16 + ra)) * PP + ks * KCH + ko;
    f32x4 accO = {0.f, 0.f, 0.f, 0.f};
    f32x4 accS = {0.f, 0.f, 0.f, 0.f};
    #pragma unroll 7
    for (int k = 0; k < KCH / 32; ++k) {
        f16x8 a = *(const f16x8*)(pa + (size_t)k * 32);
        f16x8 s = *(const f16x8*)(ps + (size_t)k * 32);
        f16x8 bb = *(const f16x8*)(pb + (size_t)k * 32);
        accO = __builtin_amdgcn_mfma_f32_16x16x32_f16(a, bb, accO, 0, 0, 0);
        accS = __builtin_amdgcn_mfma_f32_16x16x32_f16(s, bb, accS, 0, 0, 0);
    }
    int t = w * 16 + ra;
    int q = qt * 16 + (lane >> 4) * 4;
    size_t bse = (((size_t)ks * BB + b) * QP + q) * TP + t;
    #pragma unroll
    for (int r = 0; r < 4; ++r) {
        part_om[bse + (size_t)r * TP] = accO[r];
        part_s[bse + (size_t)r * TP] = accS[r];
    }
}

__global__ __launch_bounds__(256) void epilogue_kernel(
    const float* __restrict__ part_om, const float* __restrict__ part_s,
    const float* __restrict__ tmsum, const float* __restrict__ nsum,
    const float* __restrict__ ssum, const float* __restrict__ pred_logits,
    const float* __restrict__ pred_obj, const int* __restrict__ labels,
    float* __restrict__ out)
{
    int i = blockIdx.x * 256 + threadIdx.x;
    if (i >= BB * QQ * TT) return;
    int t = i % TT;
    int bq = i / TT;
    int b = bq / QQ, q = bq % QQ;
    float dO = 0.f, dS = 0.f;
    #pragma unroll
    for (int ks = 0; ks < KS; ++ks) {
        size_t o = (((size_t)ks * BB + b) * QP + q) * TP + t;
        dO += part_om[o];
        dS += part_s[o];
    }
    float ns = nsum[bq], ss = ssum[bq];
    float ts = tmsum[b * TT + t];
    float cmask = (ns - dO) * (1.f / PP);
    float cdice = 1.f - (2.f * dS + 1.f) / (ss + ts + 1.f);
    int label = labels[b * TT + t];
    float a0 = pred_obj[bq * 2], a1 = pred_obj[bq * 2 + 1];
    float prob;
    if (label == CC - 1) {
        prob = 1.f / (1.f + __expf(a0 - a1));
    } else {
        float pc = 1.f / (1.f + __expf(-pred_logits[(size_t)bq * CC + label]));
        float po = 1.f / (1.f + __expf(a1 - a0));
        prob = sqrtf(pc * po);
    }
    out[i] = 5.f * cmask - 2.f * prob + 5.f * cdice;
}

extern "C" void kernel_launch(void* const* d_in, const int* in_sizes, int n_in,
                              void* d_out, int out_size, void* d_ws, size_t ws_size,
                              hipStream_t stream) {
    const float* pred_logits = (const float*)d_in[0];
    const float* pred_obj    = (const float*)d_in[1];
    const float* pred_masks  = (const float*)d_in[2];
    const float* tgt_masks   = (const float*)d_in[3];
    const int*   tgt_labels  = (const int*)d_in[4];
    const float* coords      = (const float*)d_in[5];
    float* out = (float*)d_out;

    char* ws = (char*)d_ws;
    const size_t SZ_TB = (size_t)BB * PP * 16;           // 1,605,632
    const size_t SZ_OM = (size_t)BB * QP * PP * 2;       // 22,478,848
    const size_t SZ_TM = (size_t)BB * TP * PP * 2;       // 12,845,056
    const size_t SZ_PT = (size_t)KS * BB * QP * TP * 4;  // 1,835,008
    uint4* stb    = (uint4*)ws;
    _Float16* om  = (_Float16*)(ws + SZ_TB);
    _Float16* sg  = (_Float16*)(ws + SZ_TB + SZ_OM);
    _Float16* tmm = (_Float16*)(ws + SZ_TB + 2 * SZ_OM);
    float* part_om = (float*)(ws + SZ_TB + 2 * SZ_OM + SZ_TM);
    float* part_s  = (float*)(ws + SZ_TB + 2 * SZ_OM + SZ_TM + SZ_PT);
    float* tmsum   = (float*)(ws + SZ_TB + 2 * SZ_OM + SZ_TM + 2 * SZ_PT);
    float* nsum    = tmsum + BB * TT;
    float* ssum    = nsum + BB * QQ;

    hipLaunchKernelGGL(sort_kernel, dim3(BB * 16), dim3(256), 0, stream,
                       coords, stb);
    hipLaunchKernelGGL(sample_kernel, dim3(NMASK), dim3(512), 0, stream,
                       tgt_masks, pred_masks, stb, tmm, om, sg, tmsum, nsum, ssum);
    hipLaunchKernelGGL(dot_mfma_kernel, dim3(QP / 16, BB, KS), dim3(256), 0, stream,
                       om, sg, tmm, part_om, part_s);
    hipLaunchKernelGGL(epilogue_kernel, dim3((BB * QQ * TT + 255) / 256), dim3(256),
                       0, stream,
                       part_om, part_s, tmsum, nsum, ssum,
                       pred_logits, pred_obj, tgt_labels, out);
}

// Round 10
// 153.440 us; speedup vs baseline: 1.7021x; 1.7021x over previous
//
#include <hip/hip_runtime.h>
#include <math.h>

#define BB 8
#define QQ 100
#define CC 41
#define TT 50
#define PP 12544        // = 49 * 256
#define QP 112          // padded Q rows (7 * 16)
#define TP 64           // padded T rows (4 * 16)
#define KS 8            // split-K over P
#define KCH (PP / KS)   // 1568
#define NT (BB * TT)    // 400
#define NMASK (NT + BB * QQ)   // 1200
#define NBIN 8          // 32-row bins
#define CROWS 33        // staged rows per chunk (32 + 1 halo)

typedef _Float16 f16x8 __attribute__((ext_vector_type(8)));
typedef float f32x4 __attribute__((ext_vector_type(4)));

// ---------------------------------------------------------------------------
// sort_kernel: block (b,bin) of 512 thr. Deterministic ballot-scan counting
// sort of batch b's points into 8 32-row bins (bin = clamp(floor(y),0,255)>>5).
// Emits per-point LDS-local gather entries in sorted order:
//   t.x = (r0-32*bin)*256+xb   t.y = (r1-32*bin)*256+xb   (element idx in chunk)
//   t.z = (wa,wb) f16x2 x-weights (border-folded)
//   t.w = (ya,yb) f16x2 y-weights (border-folded)
// Also writes binStart[b*9 + 0..8].
// ---------------------------------------------------------------------------
__global__ __launch_bounds__(512) void sort_kernel(
    const float* __restrict__ coords, uint4* __restrict__ stb,
    int* __restrict__ binStart)
{
    int b = blockIdx.x >> 3;
    int mybin = blockIdx.x & 7;
    int tid = threadIdx.x;
    int lane = tid & 63, w = tid >> 6;
    const float2* cd = (const float2*)coords + (size_t)b * PP;
    __shared__ int hist[NBIN];
    __shared__ int woff[8];
    __shared__ int running;
    if (tid < NBIN) hist[tid] = 0;
    __syncthreads();
    for (int p = tid; p < PP; p += 512) {
        float y = fmaf(cd[p].y, 256.f, -0.5f);
        int y0 = (int)floorf(y);
        int bin = min(max(y0, 0), 255) >> 5;
        atomicAdd(&hist[bin], 1);
    }
    __syncthreads();
    int start = 0;
    for (int i = 0; i < mybin; ++i) start += hist[i];
    if (tid == 0) {
        running = 0;
        binStart[b * 9 + mybin] = start;
        if (mybin == 7) binStart[b * 9 + 8] = PP;
    }
    __syncthreads();

    uint4* out = stb + (size_t)b * PP;
    for (int c = 0; c < 25; ++c) {
        int p = c * 512 + tid;
        bool inb = p < PP;
        float cx = 0.f, cy = 0.f;
        if (inb) { float2 t = cd[p]; cx = t.x; cy = t.y; }
        float x = fmaf(cx, 256.f, -0.5f);
        float y = fmaf(cy, 256.f, -0.5f);
        float x0f = floorf(x), y0f = floorf(y);
        int x0 = (int)x0f, y0 = (int)y0f;
        int bin = min(max(y0, 0), 255) >> 5;
        bool match = inb && (bin == mybin);
        unsigned long long bal = __ballot(match);
        if (lane == 0) woff[w] = (int)__popcll(bal);
        __syncthreads();
        int wbase = 0;
        #pragma unroll
        for (int i = 0; i < 8; ++i) if (i < w) wbase += woff[i];
        int tot = woff[0] + woff[1] + woff[2] + woff[3]
                + woff[4] + woff[5] + woff[6] + woff[7];
        if (match) {
            int rk = (int)__popcll(bal & ((1ull << lane) - 1ull));
            float wx = x - x0f, wy = y - y0f;
            int xb = min(max(x0, 0), 254);
            int r0 = min(max(y0, 0), 255);
            int r1 = min(y0 + 1, 255);
            int base = mybin * 32;
            float wa, wb;
            if (x0 < 0)        { wa = wx;       wb = 0.f; }
            else if (x0 > 254) { wa = 0.f;      wb = 1.f - wx; }
            else               { wa = 1.f - wx; wb = wx; }
            float ya = (y0 >= 0)  ? 1.f - wy : 0.f;
            float yb = (y0 < 255) ? wy       : 0.f;
            union { unsigned int u; _Float16 h[2]; } pw, pyw;
            pw.h[0] = (_Float16)wa;  pw.h[1] = (_Float16)wb;
            pyw.h[0] = (_Float16)ya; pyw.h[1] = (_Float16)yb;
            uint4 t;
            t.x = (unsigned int)((r0 - base) * 256 + xb);
            t.y = (unsigned int)((r1 - base) * 256 + xb);
            t.z = pw.u; t.w = pyw.u;
            out[start + running + wbase + rk] = t;
        }
        __syncthreads();
        if (tid == 0) running += tot;
        __syncthreads();
    }
}

// ---------------------------------------------------------------------------
// sample_kernel: one block (1024 thr) per mask. 8 chunks of 33 fp32 rows,
// double-buffered in LDS (2 x 33 KB -> 2 blocks/CU). Per chunk: issue next
// chunk's register loads (T14), sample current bin's points from LDS, then
// write regs -> other buffer. HBM latency hides under LDS gather+math.
// ---------------------------------------------------------------------------
__global__ __launch_bounds__(1024, 8) void sample_kernel(
    const float* __restrict__ tgt_masks, const float* __restrict__ pred_masks,
    const uint4* __restrict__ stb, const int* __restrict__ binStart,
    _Float16* __restrict__ tm, _Float16* __restrict__ om, _Float16* __restrict__ sg,
    float* __restrict__ tmsum, float* __restrict__ nsum, float* __restrict__ ssum)
{
    __shared__ float buf[2][CROWS * 256];     // 2 x 33,792 B
    __shared__ float red[16], red2[16];
    int id = blockIdx.x;
    int tid = threadIdx.x;
    bool is_t = id < NT;
    int b;
    const float* m;
    _Float16* dst;
    _Float16* dsg = nullptr;
    if (is_t) {
        b = id / TT;
        m = tgt_masks + (size_t)id * 65536;
        dst = tm + ((size_t)b * TP + (id % TT)) * PP;
    } else {
        int bq = id - NT;
        b = bq / QQ;
        m = pred_masks + (size_t)bq * 65536;
        dst = om + ((size_t)b * QP + (bq % QQ)) * PP;
        dsg = sg + ((size_t)b * QP + (bq % QQ)) * PP;
    }
    const uint4* tb = stb + (size_t)b * PP;
    const int* bs = binStart + b * 9;

    uint4 ra, rb, rc;
    // ---- stage chunk 0 (rows 0..32) ----
    {
        const uint4* src = (const uint4*)m;
        ra = src[tid]; rb = src[tid + 1024];
        if (tid < CROWS * 64 - 2048) rc = src[tid + 2048];
        uint4* dl = (uint4*)buf[0];
        dl[tid] = ra; dl[tid + 1024] = rb;
        if (tid < CROWS * 64 - 2048) dl[tid + 2048] = rc;
    }
    __syncthreads();

    float l1 = 0.f, l2 = 0.f;
    for (int c = 0; c < NBIN; ++c) {
        // ---- issue next chunk's loads (registers) ----
        int nvn = 0;
        if (c < NBIN - 1) {
            int rowb = (c + 1) * 32;
            int nrow = min(CROWS, 256 - rowb);
            nvn = nrow * 64;
            const uint4* src = (const uint4*)(m + rowb * 256);
            ra = src[tid]; rb = src[tid + 1024];
            if (tid < nvn - 2048) rc = src[tid + 2048];
        }
        // ---- sample this bin's points from LDS ----
        const float* bufc = buf[c & 1];
        int pe = bs[c + 1];
        for (int p = bs[c] + tid; p < pe; p += 1024) {
            uint4 t = tb[p];
            float v00 = bufc[t.x], v01 = bufc[t.x + 1];
            float v10 = bufc[t.y], v11 = bufc[t.y + 1];
            union { unsigned int u; _Float16 h[2]; } pw, pyw;
            pw.u = t.z; pyw.u = t.w;
            float wa = (float)pw.h[0], wb = (float)pw.h[1];
            float ya = (float)pyw.h[0], yb = (float)pyw.h[1];
            float v = ya * fmaf(wa, v00, wb * v01) + yb * fmaf(wa, v10, wb * v11);
            dst[p] = (_Float16)v;
            if (is_t) {
                l1 += v;
            } else {
                float e = __expf(-fabsf(v));
                float q = 1.f / (1.f + e);
                float g = (v >= 0.f) ? q : e * q;
                dsg[p] = (_Float16)g;
                l1 += fmaxf(v, 0.f) + __logf(1.f + e);
                l2 += g;
            }
        }
        // ---- commit next chunk to the other buffer ----
        if (c < NBIN - 1) {
            uint4* dl = (uint4*)buf[(c + 1) & 1];
            dl[tid] = ra; dl[tid + 1024] = rb;
            if (tid < nvn - 2048) dl[tid + 2048] = rc;
        }
        __syncthreads();
    }

    #pragma unroll
    for (int off = 32; off; off >>= 1) {
        l1 += __shfl_down(l1, off, 64);
        l2 += __shfl_down(l2, off, 64);
    }
    if ((tid & 63) == 0) { red[tid >> 6] = l1; red2[tid >> 6] = l2; }
    __syncthreads();
    if (tid == 0) {
        float t1 = 0.f, t2 = 0.f;
        #pragma unroll
        for (int w = 0; w < 16; ++w) { t1 += red[w]; t2 += red2[w]; }
        if (is_t) tmsum[id] = t1;
        else { nsum[id - NT] = t1; ssum[id - NT] = t2; }
    }
}

// grid (7 qt, 8 b, KS). 4 waves; wave w owns t-tile w. C1=om.tm^T, C2=sig.tm^T.
__global__ __launch_bounds__(256) void dot_mfma_kernel(
    const _Float16* __restrict__ om, const _Float16* __restrict__ sg,
    const _Float16* __restrict__ tm,
    float* __restrict__ part_om, float* __restrict__ part_s)
{
    int qt = blockIdx.x, b = blockIdx.y, ks = blockIdx.z;
    int tid = threadIdx.x, lane = tid & 63, w = tid >> 6;
    int ra = lane & 15;
    int ko = (lane >> 4) * 8;
    const _Float16* pa = om + ((size_t)(b * QP + qt * 16 + ra)) * PP + ks * KCH + ko;
    const _Float16* ps = sg + ((size_t)(b * QP + qt * 16 + ra)) * PP + ks * KCH + ko;
    const _Float16* pb = tm + ((size_t)(b * TP + w * 16 + ra)) * PP + ks * KCH + ko;
    f32x4 accO = {0.f, 0.f, 0.f, 0.f};
    f32x4 accS = {0.f, 0.f, 0.f, 0.f};
    #pragma unroll 7
    for (int k = 0; k < KCH / 32; ++k) {
        f16x8 a = *(const f16x8*)(pa + (size_t)k * 32);
        f16x8 s = *(const f16x8*)(ps + (size_t)k * 32);
        f16x8 bb = *(const f16x8*)(pb + (size_t)k * 32);
        accO = __builtin_amdgcn_mfma_f32_16x16x32_f16(a, bb, accO, 0, 0, 0);
        accS = __builtin_amdgcn_mfma_f32_16x16x32_f16(s, bb, accS, 0, 0, 0);
    }
    int t = w * 16 + ra;
    int q = qt * 16 + (lane >> 4) * 4;
    size_t bse = (((size_t)ks * BB + b) * QP + q) * TP + t;
    #pragma unroll
    for (int r = 0; r < 4; ++r) {
        part_om[bse + (size_t)r * TP] = accO[r];
        part_s[bse + (size_t)r * TP] = accS[r];
    }
}

__global__ __launch_bounds__(256) void epilogue_kernel(
    const float* __restrict__ part_om, const float* __restrict__ part_s,
    const float* __restrict__ tmsum, const float* __restrict__ nsum,
    const float* __restrict__ ssum, const float* __restrict__ pred_logits,
    const float* __restrict__ pred_obj, const int* __restrict__ labels,
    float* __restrict__ out)
{
    int i = blockIdx.x * 256 + threadIdx.x;
    if (i >= BB * QQ * TT) return;
    int t = i % TT;
    int bq = i / TT;
    int b = bq / QQ, q = bq % QQ;
    float dO = 0.f, dS = 0.f;
    #pragma unroll
    for (int ks = 0; ks < KS; ++ks) {
        size_t o = (((size_t)ks * BB + b) * QP + q) * TP + t;
        dO += part_om[o];
        dS += part_s[o];
    }
    float ns = nsum[bq], ss = ssum[bq];
    float ts = tmsum[b * TT + t];
    float cmask = (ns - dO) * (1.f / PP);
    float cdice = 1.f - (2.f * dS + 1.f) / (ss + ts + 1.f);
    int label = labels[b * TT + t];
    float a0 = pred_obj[bq * 2], a1 = pred_obj[bq * 2 + 1];
    float prob;
    if (label == CC - 1) {
        prob = 1.f / (1.f + __expf(a0 - a1));
    } else {
        float pc = 1.f / (1.f + __expf(-pred_logits[(size_t)bq * CC + label]));
        float po = 1.f / (1.f + __expf(a1 - a0));
        prob = sqrtf(pc * po);
    }
    out[i] = 5.f * cmask - 2.f * prob + 5.f * cdice;
}

extern "C" void kernel_launch(void* const* d_in, const int* in_sizes, int n_in,
                              void* d_out, int out_size, void* d_ws, size_t ws_size,
                              hipStream_t stream) {
    const float* pred_logits = (const float*)d_in[0];
    const float* pred_obj    = (const float*)d_in[1];
    const float* pred_masks  = (const float*)d_in[2];
    const float* tgt_masks   = (const float*)d_in[3];
    const int*   tgt_labels  = (const int*)d_in[4];
    const float* coords      = (const float*)d_in[5];
    float* out = (float*)d_out;

    char* ws = (char*)d_ws;
    const size_t SZ_TB = (size_t)BB * PP * 16;           // 1,605,632
    const size_t SZ_BS = 1024;                           // binStart (288 B used)
    const size_t SZ_OM = (size_t)BB * QP * PP * 2;       // 22,478,848
    const size_t SZ_TM = (size_t)BB * TP * PP * 2;       // 12,845,056
    const size_t SZ_PT = (size_t)KS * BB * QP * TP * 4;  // 1,835,008
    uint4* stb    = (uint4*)ws;
    int* binStart = (int*)(ws + SZ_TB);
    _Float16* om  = (_Float16*)(ws + SZ_TB + SZ_BS);
    _Float16* sg  = (_Float16*)(ws + SZ_TB + SZ_BS + SZ_OM);
    _Float16* tmm = (_Float16*)(ws + SZ_TB + SZ_BS + 2 * SZ_OM);
    float* part_om = (float*)(ws + SZ_TB + SZ_BS + 2 * SZ_OM + SZ_TM);
    float* part_s  = (float*)(ws + SZ_TB + SZ_BS + 2 * SZ_OM + SZ_TM + SZ_PT);
    float* tmsum   = (float*)(ws + SZ_TB + SZ_BS + 2 * SZ_OM + SZ_TM + 2 * SZ_PT);
    float* nsum    = tmsum + BB * TT;
    float* ssum    = nsum + BB * QQ;

    hipLaunchKernelGGL(sort_kernel, dim3(BB * NBIN), dim3(512), 0, stream,
                       coords, stb, binStart);
    hipLaunchKernelGGL(sample_kernel, dim3(NMASK), dim3(1024), 0, stream,
                       tgt_masks, pred_masks, stb, binStart,
                       tmm, om, sg, tmsum, nsum, ssum);
    hipLaunchKernelGGL(dot_mfma_kernel, dim3(QP / 16, BB, KS), dim3(256), 0, stream,
                       om, sg, tmm, part_om, part_s);
    hipLaunchKernelGGL(epilogue_kernel, dim3((BB * QQ * TT + 255) / 256), dim3(256),
                       0, stream,
                       part_om, part_s, tmsum, nsum, ssum,
                       pred_logits, pred_obj, tgt_labels, out);
}